// Round 18
// baseline (75.281 us; speedup 1.0000x reference)
//
#include <hip/hip_runtime.h>

#define NB      2000
#define NT      365
#define LENF    15
#define PSTRIDE 96              // 12 params * 8 muls, floats per (b,t)
#define CH      16              // timesteps per chunk
#define NFULL   22              // full chunks (352 steps)
#define NCHUNK  23              // incl. 13-step tail
#define CHBYTES (CH * PSTRIDE * 4)              // 6144 B per chunk per basin
#define BASIN_BYTES (NT * PSTRIDE * 4)          // 140160
#define CLAMP16     (BASIN_BYTES - 16)          // 140144
#define PARW    1544            // LDS words per basin param block (1536 + 8 pad; 1544%32==8)
#define FRCW    68              // LDS words per basin forcing block: 16 steps x 4 + 4 pad
// VMEM ops per ISSUE = 12 GLD16 + 2 GLD4 = 14 -> main-loop wait is vmcnt(14)

#define GLD16(g, l) __builtin_amdgcn_global_load_lds( \
    (const __attribute__((address_space(1))) void*)(g), \
    (__attribute__((address_space(3))) void*)(l), 16, 0, 0)
#define GLD4(g, l) __builtin_amdgcn_global_load_lds( \
    (const __attribute__((address_space(1))) void*)(g), \
    (__attribute__((address_space(3))) void*)(l), 4, 0, 0)

#define EXP2F(x) __builtin_amdgcn_exp2f(x)
#define LOG2F(x) __builtin_amdgcn_logf(x)
#define LOG2E    1.44269504088896f

// DPP cross-lane ops — pure VALU, no LDS pipe, no lgkmcnt.
template <int CTRL>
__device__ __forceinline__ float dpp_mov(float x) {
  int xi = __float_as_int(x);
  int r  = __builtin_amdgcn_update_dpp(xi, xi, CTRL, 0xF, 0xF, true);
  return __int_as_float(r);
}
#define DPP_XOR1   0xB1    // quad_perm [1,0,3,2]
#define DPP_XOR2   0x4E    // quad_perm [2,3,0,1]
#define DPP_HMIRR  0x141   // row_half_mirror: i <-> 7-i within each 8-lane half

// TWO BASINS PER WAVE (lane = d*16 + bsel*8 + m), 1000 blocks -> ~4 waves/CU.
// Best verified configuration (R15, 75.3us): GLD16 depth-2 chunk staging with
// counted vmcnt(14); 3-slot (s+2 lookahead) register rotation of the 9 param
// b32 reads + 1 forcing b128 read per step; DPP-only mul-mean; batched float4
// Q writes; fused gamma-routing conv (gammaln/th^aa cancels under norm).
// The manual-lgkmcnt asm variants (R16/R17) NaN'd — ds_read2's counter
// semantics are unverifiable here; this compiler-managed form is the keeper.
__global__ __launch_bounds__(64) void prms_kernel(
    const float* __restrict__ P, const float* __restrict__ Ep,
    const float* __restrict__ Tair, const float* __restrict__ params,
    const float* __restrict__ rout_a, const float* __restrict__ rout_b,
    float* __restrict__ out)
{
  __shared__ __attribute__((aligned(16))) float sh_par[2][2 * PARW];  // 24704 B
  __shared__ __attribute__((aligned(16))) float sh_frc[2][2][FRCW];   //  1088 B
  __shared__ __attribute__((aligned(16))) float Qs[2][NT + 3];        //  2944 B

  const int lane = threadIdx.x;        // 0..63
  const int m    = lane & 7;           // mul index
  const int bsel = (lane >> 3) & 1;    // which of the wave's 2 basins
  const int b0   = blockIdx.x * 2;     // first basin of this block

  // preload routing params early — latency hidden under the scan
  const float ra0 = rout_a[b0],     rb0 = rout_b[b0];
  const float ra1 = rout_a[b0 + 1], rb1 = rout_b[b0 + 1];

  const char* pbg[2] = {
    (const char*)(params + (size_t)b0 * (NT * PSTRIDE)),
    (const char*)(params + (size_t)(b0 + 1) * (NT * PSTRIDE)) };

  // forcing staging: lane -> (step fl_s = lane>>2, array fl_arr = lane&3);
  // arr 3 duplicates Tair into the pad word (never read)
  const int fl_s   = lane >> 2;
  const int fl_arr = (lane & 3) > 2 ? 2 : (lane & 3);
  const float* fsrcs[2][3] = {
    { P + (size_t)b0 * NT,       Ep + (size_t)b0 * NT,       Tair + (size_t)b0 * NT },
    { P + (size_t)(b0 + 1) * NT, Ep + (size_t)(b0 + 1) * NT, Tair + (size_t)(b0 + 1) * NT } };

  // ---- staging: 12x GLD16 (params) + 2x GLD4 (forcings) per chunk ----
  auto ISSUE = [&](int c, int buf) {
    #pragma unroll
    for (int bs = 0; bs < 2; ++bs) {
      #pragma unroll
      for (int j = 0; j < 6; ++j) {
        int off = c * CHBYTES + j * 1024 + lane * 16;
        off = off > CLAMP16 ? CLAMP16 : off;   // tail clamp (dups land in pad)
        GLD16(pbg[bs] + off, &sh_par[buf][bs * PARW + j * 256]);
      }
    }
    #pragma unroll
    for (int bs = 0; bs < 2; ++bs) {
      int ft = c * CH + fl_s;
      ft = ft > NT - 1 ? NT - 1 : ft;
      GLD4(fsrcs[bs][fl_arr] + ft, &sh_frc[buf][bs][0]);  // lane L -> word L = s*4+arr
    }
  };

  float S1 = 0.5f, S2 = 0.5f, S3 = 0.5f, S4 = 0.5f, S5 = 0.5f;
  const int pbase = bsel * PARW + m;    // thread-const param word base

  // ---- per-step LDS->register loads: 9 param b32 (pair-mergeable) ----
  auto LOADR = [&](int buf, int s, float* r) {
    const float* par = &sh_par[buf][pbase + s * PSTRIDE];
    r[0] = par[0];   r[1] = par[8];   r[2] = par[24];
    r[3] = par[32];  r[4] = par[40];  r[5] = par[48];
    r[6] = par[64];  r[7] = par[72];  r[8] = par[80];
  };

  // returns this thread's reduced Q (valid on lanes 0,8 after DPP chain)
  auto STEPQ = [&](const float* d, float4 fv) -> float {
    const float tt    = fmaf(d[0], 8.0f, -3.0f);
    const float ddf   = d[1] * 20.0f;
    const float Smax3 = fmaf(d[2], 680.0f, 20.0f);
    const float p_lo  = fmaf(d[3], 0.99f, 0.005f);
    const float p_hi  = fmaf(d[4], 0.99f, 0.005f);
    const float p_exp = fmaf(d[5], 4.0f, 1.0f);
    const float i1    = d[6];
    const float i2    = d[7] * 0.001f;
    const float kb    = d[8];
    const float Pt    = fv.x;
    const float Ept   = fv.y;
    const float Tt    = fv.z;

    const float snow = (Tt <= tt) ? Pt : 0.0f;
    const float rain = Pt - snow;
    const float melt = fmaxf(fminf(ddf * (Tt - tt), S1), 0.0f);   // DT=1
    S1 = S1 + snow - melt;

    const float inter = rain * 0.95f;
    const float evap2 = fminf(S2, Ept);
    S2 = fmaxf(S2 + (rain - inter) - evap2, 0.0f);

    const float infil  = melt + inter;
    const float frac   = fmaxf(S3, 0.0f) * __builtin_amdgcn_rcpf(Smax3);
    const float satexc = (p_lo + (p_hi - p_lo) * frac) * infil;
    const float rem    = fmaxf(infil - satexc, 0.0f);
    // frac^p_exp: frac==0 -> log2=-inf -> exp2(-inf)=0 (matches 0**p, p>=1)
    const float rech   = rem * EXP2F(p_exp * LOG2F(frac));
    const float evap3  = fminf(frac * Ept, S3);
    S3 = S3 + rem - rech - evap3;

    const float S4c   = fmaxf(S4, 0.0f);
    const float iflow = fminf(S4c, fmaf(i2, S4c * S4c, i1 * S4c));
    S4 = S4 + rech - iflow;

    const float base = kb * S5;
    S5 = S5 + iflow - base;

    float q = satexc + base;
    q += dpp_mov<DPP_XOR1>(q);
    q += dpp_mov<DPP_XOR2>(q);
    q += dpp_mov<DPP_HMIRR>(q);
    return q * 0.125f;
  };

  // ---- depth-2 chunk pipeline; 3-slot (s+2) register rotation inside ----
  float r[3][9];
  float4 fv[3];
  float qv[CH];                          // statically indexed (unrolled s)
  ISSUE(0, 0);
  ISSUE(1, 1);
  for (int c = 0; c < NFULL; ++c) {
    asm volatile("s_waitcnt vmcnt(14)" ::: "memory");   // chunk c resident (c+1 in flight)
    const int buf = c & 1;
    const float4* fp = (const float4*)&sh_frc[buf][bsel][0];
    LOADR(buf, 0, r[0]); fv[0] = fp[0];
    LOADR(buf, 1, r[1]); fv[1] = fp[1];
    #pragma unroll
    for (int s = 0; s < CH; ++s) {
      if (s + 2 < CH) { LOADR(buf, s + 2, r[(s + 2) % 3]); fv[(s + 2) % 3] = fp[s + 2]; }
      qv[s] = STEPQ(r[s % 3], fv[s % 3]);
    }
    if ((lane & 55) == 0) {              // lanes 0 (basin0) and 8 (basin1)
      const int t0 = c * CH;
      *(float4*)&Qs[bsel][t0]      = make_float4(qv[0],  qv[1],  qv[2],  qv[3]);
      *(float4*)&Qs[bsel][t0 + 4]  = make_float4(qv[4],  qv[5],  qv[6],  qv[7]);
      *(float4*)&Qs[bsel][t0 + 8]  = make_float4(qv[8],  qv[9],  qv[10], qv[11]);
      *(float4*)&Qs[bsel][t0 + 12] = make_float4(qv[12], qv[13], qv[14], qv[15]);
    }
    asm volatile("s_waitcnt lgkmcnt(0)" ::: "memory");  // reads of buf drained
    if (c + 2 < NCHUNK) ISSUE(c + 2, buf);
  }
  // tail chunk (c = 22): 13 valid steps, buf = 0
  asm volatile("s_waitcnt vmcnt(0)" ::: "memory");
  {
    const float4* fp = (const float4*)&sh_frc[0][bsel][0];
    LOADR(0, 0, r[0]); fv[0] = fp[0];
    LOADR(0, 1, r[1]); fv[1] = fp[1];
    #pragma unroll
    for (int s = 0; s < 13; ++s) {
      if (s + 2 < 13) { LOADR(0, s + 2, r[(s + 2) % 3]); fv[(s + 2) % 3] = fp[s + 2]; }
      qv[s] = STEPQ(r[s % 3], fv[s % 3]);
    }
    if ((lane & 55) == 0) {
      *(float4*)&Qs[bsel][352] = make_float4(qv[0], qv[1], qv[2],  qv[3]);
      *(float4*)&Qs[bsel][356] = make_float4(qv[4], qv[5], qv[6],  qv[7]);
      *(float4*)&Qs[bsel][360] = make_float4(qv[8], qv[9], qv[10], qv[11]);
      Qs[bsel][364] = qv[12];
    }
  }

  __syncthreads();

  // ---- fused gamma routing conv, per basin (all 64 lanes) ----
  #pragma unroll
  for (int bs = 0; bs < 2; ++bs) {
    const float ra_v = bs ? ra1 : ra0;
    const float rb_v = bs ? rb1 : rb0;
    const float aa  = fmaxf(ra_v * 2.9f, 0.0f) + 0.1f;
    const float th  = fmaxf(rb_v * 6.5f, 0.0f) + 0.5f;
    const float am1 = aa - 1.0f;
    const float ith = -LOG2E / th;

    float w[LENF];
    float wsum = 0.0f;
    #pragma unroll
    for (int j = 0; j < LENF; ++j) {
      const float tj = (float)j + 0.5f;
      w[j] = EXP2F(fmaf(am1, LOG2F(tj), tj * ith));
      wsum += w[j];
    }
    const float inv = 1.0f / wsum;
    #pragma unroll
    for (int j = 0; j < LENF; ++j) w[j] *= inv;

    float* __restrict__ ob = out + (size_t)(b0 + bs) * NT;
    #pragma unroll
    for (int k = 0; k < 6; ++k) {
      const int t = lane + k * 64;
      if (t < NT) {
        float acc = 0.0f;
        #pragma unroll
        for (int j = 0; j < LENF; ++j) {
          const int idx = t - j;
          if (idx >= 0) acc += w[j] * Qs[bs][idx];
        }
        ob[t] = acc;
      }
    }
  }
}

extern "C" void kernel_launch(void* const* d_in, const int* in_sizes, int n_in,
                              void* d_out, int out_size, void* d_ws, size_t ws_size,
                              hipStream_t stream) {
  const float* P      = (const float*)d_in[0];
  const float* Ep     = (const float*)d_in[1];
  const float* Tair   = (const float*)d_in[2];
  const float* params = (const float*)d_in[3];
  const float* ra     = (const float*)d_in[4];
  const float* rb     = (const float*)d_in[5];
  float* out = (float*)d_out;

  prms_kernel<<<NB / 2, 64, 0, stream>>>(P, Ep, Tair, params, ra, rb, out);
}